// Round 20
// baseline (162.899 us; speedup 1.0000x reference)
//
#include <hip/hip_runtime.h>

// Problem constants
#define EMB  4096
#define DH   128      // QKV_DIM
#define NH   32       // N_HEADS
#define NTOK 16384    // B*S
#define NCOL 384      // qs | k | v columns

// Fused tile: 64(M) x 384(N=all) block, BK=64, 8 waves, wave tile 64x48 (acc 4x3)
#define BM 64
#define BK 64

typedef __attribute__((ext_vector_type(8))) short short8;
typedef __attribute__((ext_vector_type(4))) short short4_t;
typedef __attribute__((ext_vector_type(4))) float f32x4;

// f32 pair -> packed bf16x2, RNE (hardware cvt)
static __device__ __forceinline__ unsigned int cvt2(float a, float b) {
    unsigned int r;
    asm volatile("v_cvt_pk_bf16_f32 %0, %1, %2" : "=v"(r) : "v"(a), "v"(b));
    return r;
}
// scalar f32 -> bf16 bits, RNE (prep_w only)
static __device__ __forceinline__ unsigned short f2bf(float f) {
    unsigned int u = __builtin_bit_cast(unsigned int, f);
    u += 0x7fffu + ((u >> 16) & 1u);
    return (unsigned short)(u >> 16);
}
// single-instruction hardware exp2 (validated R13-R19: within threshold)
static __device__ __forceinline__ float exp2_hw(float x) {
#if __has_builtin(__builtin_amdgcn_exp2f)
    return __builtin_amdgcn_exp2f(x);
#else
    float r;
    asm volatile("v_exp_f32 %0, %1\n\ts_nop 1" : "=v"(r) : "v"(x));
    return r;
#endif
}

// ---------------------------------------------------------------------------
// Kernel 1: build W3F — combined weights W3[384][4096] (bf16) in MFMA
// FRAGMENT-LINEAR order (proven R10-R19): panel p (=n>>6), k-tile kt (=D>>6),
// chunk (kh*4+jfr), lane: the 16 B at
//   byte = p*524288 + kt*8192 + (kh*4+jfr)*1024 + lane*16
// hold B[n=jfr*16+lmod][D=kt*64+kh*32+lgrp*8+e] — one lane's B-fragment.
// Also bias[384].
// ---------------------------------------------------------------------------
__global__ void prep_w(const float* __restrict__ Wq, const float* __restrict__ bq,
                       const float* __restrict__ Wk, const float* __restrict__ bk,
                       const float* __restrict__ Wv, const float* __restrict__ bv,
                       unsigned short* __restrict__ W3F, float* __restrict__ bias) {
    const int tid = blockIdx.x * 256 + threadIdx.x;   // [0, 384*512)
    const int n  = tid >> 9;          // output column [0,384)
    const int ck = tid & 511;         // 8-element chunk of the 4096 K dim
    const int D0 = ck * 8;

    float v[8];
    if (n < DH) {
#pragma unroll
        for (int e = 0; e < 8; ++e) {
            const float4* p = (const float4*)(Wq + (size_t)(D0 + e) * (DH * NH) + n * NH);
            float s = 0.f;
#pragma unroll
            for (int i = 0; i < 8; ++i) { float4 q = p[i]; s += (q.x + q.y) + (q.z + q.w); }
            v[e] = s;
        }
    } else if (n < 2 * DH) {
#pragma unroll
        for (int e = 0; e < 8; ++e) v[e] = Wk[(size_t)(D0 + e) * DH + (n - DH)];
    } else {
#pragma unroll
        for (int e = 0; e < 8; ++e) v[e] = Wv[(size_t)(D0 + e) * DH + (n - 2 * DH)];
    }

    union { short8 s; unsigned int u[4]; } pk;
#pragma unroll
    for (int j = 0; j < 4; ++j)
        pk.u[j] = (unsigned int)f2bf(v[2 * j]) | ((unsigned int)f2bf(v[2 * j + 1]) << 16);

    const int p    = n >> 6, r = n & 63;
    const int jfr  = r >> 4, lmod = r & 15;
    const int kt   = ck >> 3;
    const int kh   = (ck >> 2) & 1;
    const int lgrp = ck & 3;
    const int lane = lgrp * 16 + lmod;
    char* dst = (char*)W3F + (size_t)p * 524288 + (size_t)kt * 8192
              + (kh * 4 + jfr) * 1024 + lane * 16;
    *(short8*)dst = pk.s;

    if (ck == 0) {
        float b;
        if (n < DH) {
            float s = 0.f;
#pragma unroll
            for (int h = 0; h < NH; ++h) s += bq[n * NH + h];
            b = s;
        } else if (n < 2 * DH) {
            b = bk[n - DH];
        } else {
            b = bv[n - 2 * DH];
        }
        bias[n] = b;
    }
}

// ---------------------------------------------------------------------------
// Kernel 2 (FUSED, BM=64, 8 waves, DEEP-PIPELINED K-loop):
// - A-LDS double buffer: write tile t+1 into Abuf[(t+1)&1] while computing
//   Abuf[t&1] -> ONE lgkm+barrier per iteration (was 2).
// - X prefetch 4 tiles deep (av 4-set rotation, loop unrolled x4) -> ~3000 cy
//   slack vs HBM latency; B register-dbuf 1 tile ahead (L2-resident W3F).
// - setprio(1) around the MFMA cluster (T5; schedule is phase-split).
// - All barriers asm volatile(... ::: "memory"), counters NOT drained (R18's
//   race fix retained; loads stay in flight across barriers).
// Epilogue (R19-validated): two-pass 32-token softmax, hw exp2, race-free
// register-shfl broadcast, nt stores.
// ---------------------------------------------------------------------------
__global__ __launch_bounds__(512) void fused_mqa(const float* __restrict__ X,
                         const unsigned short* __restrict__ W3F,
                         const float* __restrict__ bias,
                         float* __restrict__ out) {
    __shared__ __align__(16) unsigned short Asm[2][BM * BK];   // 16 KB
    __shared__ float qsm[32 * NCOL];                           // 48 KB

    // XCD-bijective remap over 256 blocks (32 per XCD)
    const int bid  = blockIdx.x;
    const int wkid = (bid & 7) * 32 + (bid >> 3);
    const int m0   = wkid * BM;
    const int nt   = EMB / BK;                // 64

    const int t = threadIdx.x, lane = t & 63, w = t >> 6;   // w in {0..7}
    const int lmod = lane & 15, lgrp = lane >> 4;

    f32x4 acc[4][3] = {};

    // A staging (all 8 waves): wave w covers rows [w*8, w*8+8);
    // lane covers row w*8+(lane>>3); av[0] = k[(lane&7)*4..+4],
    // av[1] = k[32+(lane&7)*4..+4]  (each instr: 8 rows x 128B contiguous).
    const int arow = w * 8 + (lane >> 3);
    const float* xp = X + (size_t)(m0 + arow) * EMB + (lane & 7) * 4;
    const int ac0 = (lane & 7) >> 1;          // chunk of av[0] (av[1]: +4)
    const int ah4 = ((lane & 7) & 1) * 4;     // short offset within chunk

    // B source: wave w consumes frag cols f = w*3+j (48 cols), fragment-linear
    const char* bp[3];
#pragma unroll
    for (int j = 0; j < 3; ++j) {
        const int f = w * 3 + j;
        bp[j] = (const char*)W3F + (size_t)(f >> 2) * 524288 + (f & 3) * 1024 + lane * 16;
    }

    f32x4 avA[2], avB[2], avC[2], avD[2];
    short8 bfA[6], bfB[6];

#define LOAD_AV(T, AV) do { \
    const int tc_ = (T) < nt ? (T) : nt - 1; \
    AV[0] = __builtin_nontemporal_load((const f32x4*)(xp + tc_ * BK)); \
    AV[1] = __builtin_nontemporal_load((const f32x4*)(xp + tc_ * BK + 32)); \
} while (0)

#define LOAD_BF(T, BF) do { \
    const int tc_ = (T) < nt ? (T) : nt - 1; \
    _Pragma("unroll") \
    for (int j = 0; j < 3; ++j) { \
        BF[j]     = *(const short8*)(bp[j] + (size_t)tc_ * 8192); \
        BF[3 + j] = *(const short8*)(bp[j] + (size_t)tc_ * 8192 + 4096); \
    } \
} while (0)

#define WRITE_A(AV, BUF) do { \
    union { short4_t s; unsigned int u[2]; } p0, p1; \
    p0.u[0] = cvt2(AV[0].x, AV[0].y);  p0.u[1] = cvt2(AV[0].z, AV[0].w); \
    p1.u[0] = cvt2(AV[1].x, AV[1].y);  p1.u[1] = cvt2(AV[1].z, AV[1].w); \
    *(short4_t*)(&(BUF)[arow * BK + ((ac0 ^ (arow & 7)) << 3) + ah4]) = p0.s; \
    *(short4_t*)(&(BUF)[arow * BK + (((ac0 + 4) ^ (arow & 7)) << 3) + ah4]) = p1.s; \
} while (0)

#define COMPUTE(AB, BF) do { \
    __builtin_amdgcn_s_setprio(1); \
    _Pragma("unroll") \
    for (int kh = 0; kh < 2; ++kh) { \
        const int cs = ((kh * 4 + lgrp) ^ (lmod & 7)) * 8; \
        short8 af[4]; \
        _Pragma("unroll") \
        for (int i = 0; i < 4; ++i) \
            af[i] = *(const short8*)(&(AB)[(i * 16 + lmod) * BK + cs]); \
        _Pragma("unroll") \
        for (int i = 0; i < 4; ++i) \
            _Pragma("unroll") \
            for (int j = 0; j < 3; ++j) \
                acc[i][j] = __builtin_amdgcn_mfma_f32_16x16x32_bf16(af[i], BF[kh * 3 + j], acc[i][j], 0, 0, 0); \
    } \
    __builtin_amdgcn_s_setprio(0); \
} while (0)

// one barrier per iter: drain lgkm (A-tile ds ops) then barrier; counters for
// global loads NOT drained — they stay in flight across the barrier.
#define IBAR()  do { asm volatile("s_waitcnt lgkmcnt(0)\n\ts_barrier" ::: "memory"); } while (0)

    // ---- prologue: Abuf0 = tile 0; av{A..D} = x(1..4); bfA = B(0) ----
    LOAD_AV(0, avA);
    LOAD_BF(0, bfA);
    WRITE_A(avA, Asm[0]);          // waits avA (vmcnt), cvt, ds_write
    LOAD_AV(1, avA);
    LOAD_AV(2, avB);
    LOAD_AV(3, avC);
    LOAD_AV(4, avD);
    IBAR();                        // tile 0 visible block-wide

    // steady state, unrolled x4 (nt = 64):
    // iter k: WRITE_A(av[k] = x(tt+k+1) -> Abuf[(k+1)&1]); LOAD_BF(tt+k+1);
    //         LOAD_AV(tt+k+5 -> av[k]); COMPUTE(Abuf[k&1], bf); IBAR.
    for (int tt = 0; tt < nt; tt += 4) {
        WRITE_A(avA, Asm[1]);  LOAD_BF(tt + 1, bfB);  LOAD_AV(tt + 5, avA);
        COMPUTE(Asm[0], bfA);  IBAR();
        WRITE_A(avB, Asm[0]);  LOAD_BF(tt + 2, bfA);  LOAD_AV(tt + 6, avB);
        COMPUTE(Asm[1], bfB);  IBAR();
        WRITE_A(avC, Asm[1]);  LOAD_BF(tt + 3, bfB);  LOAD_AV(tt + 7, avC);
        COMPUTE(Asm[0], bfA);  IBAR();
        WRITE_A(avD, Asm[0]);  LOAD_BF(tt + 4, bfA);  LOAD_AV(tt + 8, avD);
        COMPUTE(Asm[1], bfB);  IBAR();
    }

    // ---- epilogue: two passes of 32 tokens each through the 48-KB qsm ----
    // C/D layout: col = lane&15, token-row = i*16 + (lane>>4)*4 + reg.
    const float c = 0.088388347648318447f * 1.4426950408889634f; // scale*log2(e)
#pragma unroll
    for (int pass = 0; pass < 2; ++pass) {
        __syncthreads();                      // prev pass's qsm readers done
#pragma unroll
        for (int j = 0; j < 3; ++j) {
            const int col = w * 48 + j * 16 + lmod;
            const float bj = bias[col];
#pragma unroll
            for (int i2 = 0; i2 < 2; ++i2) {
                const int row = i2 * 16 + (lgrp << 2);   // row within pass
#pragma unroll
                for (int r = 0; r < 4; ++r)
                    qsm[(row + r) * NCOL + col] = acc[pass * 2 + i2][j][r] + bj;
            }
        }
        __syncthreads();                      // qsm pass resident

        for (int tok = w; tok < 32; tok += 8) {
            const float* row = &qsm[tok * NCOL];
            const float q0  = row[lane],       q1  = row[64 + lane];
            const float kk0 = row[128 + lane], kk1 = row[192 + lane];

            float lmax = fmaxf(kk0, kk1), lmin = fminf(kk0, kk1);
#pragma unroll
            for (int off = 32; off; off >>= 1) {
                lmax = fmaxf(lmax, __shfl_xor(lmax, off));
                lmin = fminf(lmin, __shfl_xor(lmin, off));
            }

            const float a0 = q0 * c, a1 = q1 * c;
            const float m0v = (a0 >= 0.f) ? a0 * lmax : a0 * lmin;
            const float m1v = (a1 >= 0.f) ? a1 * lmax : a1 * lmin;

            float s00 = 0.f, s01 = 0.f, s10 = 0.f, s11 = 0.f;
#pragma unroll 8
            for (int e = 0; e < DH; ++e) {
                const float kv = row[128 + e];    // broadcast LDS read
                const float vv = row[256 + e];
                const float p0 = exp2_hw(fmaf(a0, kv, -m0v));
                const float p1 = exp2_hw(fmaf(a1, kv, -m1v));
                s00 += p0;  s01 = fmaf(p0, vv, s01);
                s10 += p1;  s11 = fmaf(p1, vv, s11);
            }
            const float o0 = s01 / s00;           // o[d], d = lane
            const float o1 = s11 / s10;           // o[d], d = 64 + lane

            float* orow = out + (size_t)(m0 + pass * 32 + tok) * (DH * NH);
#pragma unroll
            for (int it = 0; it < 16; ++it) {
                const int idx = it * 64 + lane;              // float4 index
                const int src = (it & 7) * 8 + (lane >> 3);  // d & 63
                const float val = (it < 8) ? __shfl(o0, src) : __shfl(o1, src);
                f32x4 f4 = {val, val, val, val};
                __builtin_nontemporal_store(f4, (f32x4*)(orow + idx * 4));
            }
        }
    }
#undef LOAD_AV
#undef LOAD_BF
#undef WRITE_A
#undef COMPUTE
#undef IBAR
}

// ---------------------------------------------------------------------------
extern "C" void kernel_launch(void* const* d_in, const int* in_sizes, int n_in,
                              void* d_out, int out_size, void* d_ws, size_t ws_size,
                              hipStream_t stream) {
    const float* x  = (const float*)d_in[0];
    const float* Wq = (const float*)d_in[1];
    const float* bq = (const float*)d_in[2];
    const float* Wk = (const float*)d_in[3];
    const float* bk = (const float*)d_in[4];
    const float* Wv = (const float*)d_in[5];
    const float* bv = (const float*)d_in[6];
    float* out = (float*)d_out;

    char* ws = (char*)d_ws;
    unsigned short* W3F = (unsigned short*)ws;       // 6*524288 = 3,145,728 B
    float* bias = (float*)(ws + 3145728);            // 1,536 B

    prep_w<<<(NCOL * 512) / 256, 256, 0, stream>>>(Wq, bq, Wk, bk, Wv, bv, W3F, bias);
    fused_mqa<<<NTOK / BM, 512, 0, stream>>>(x, W3F, bias, out);
}

// Round 21
// 159.568 us; speedup vs baseline: 1.0209x; 1.0209x over previous
//
#include <hip/hip_runtime.h>

// Problem constants
#define EMB  4096
#define DH   128      // QKV_DIM
#define NH   32       // N_HEADS
#define NTOK 16384    // B*S
#define NCOL 384      // qs | k | v columns

// Fused tile: 64(M) x 384(N=all) block, BK=64, 8 waves, wave tile 64x48 (acc 4x3)
#define BM 64
#define BK 64

typedef __attribute__((ext_vector_type(8))) short short8;
typedef __attribute__((ext_vector_type(4))) short short4_t;
typedef __attribute__((ext_vector_type(4))) float f32x4;

// f32 pair -> packed bf16x2, RNE (hardware cvt)
static __device__ __forceinline__ unsigned int cvt2(float a, float b) {
    unsigned int r;
    asm volatile("v_cvt_pk_bf16_f32 %0, %1, %2" : "=v"(r) : "v"(a), "v"(b));
    return r;
}
// scalar f32 -> bf16 bits, RNE (prep_w only)
static __device__ __forceinline__ unsigned short f2bf(float f) {
    unsigned int u = __builtin_bit_cast(unsigned int, f);
    u += 0x7fffu + ((u >> 16) & 1u);
    return (unsigned short)(u >> 16);
}
// single-instruction hardware exp2 (validated R13-R20: within threshold)
static __device__ __forceinline__ float exp2_hw(float x) {
#if __has_builtin(__builtin_amdgcn_exp2f)
    return __builtin_amdgcn_exp2f(x);
#else
    float r;
    asm volatile("v_exp_f32 %0, %1\n\ts_nop 1" : "=v"(r) : "v"(x));
    return r;
#endif
}

// ---------------------------------------------------------------------------
// Kernel 1: build W3F — combined weights W3[384][4096] (bf16) in MFMA
// FRAGMENT-LINEAR order (proven R10-R20): panel p (=n>>6), k-tile kt (=D>>6),
// chunk (kh*4+jfr), lane: the 16 B at
//   byte = p*524288 + kt*8192 + (kh*4+jfr)*1024 + lane*16
// hold B[n=jfr*16+lmod][D=kt*64+kh*32+lgrp*8+e] — one lane's B-fragment.
// Also bias[384].
// ---------------------------------------------------------------------------
__global__ void prep_w(const float* __restrict__ Wq, const float* __restrict__ bq,
                       const float* __restrict__ Wk, const float* __restrict__ bk,
                       const float* __restrict__ Wv, const float* __restrict__ bv,
                       unsigned short* __restrict__ W3F, float* __restrict__ bias) {
    const int tid = blockIdx.x * 256 + threadIdx.x;   // [0, 384*512)
    const int n  = tid >> 9;          // output column [0,384)
    const int ck = tid & 511;         // 8-element chunk of the 4096 K dim
    const int D0 = ck * 8;

    float v[8];
    if (n < DH) {
#pragma unroll
        for (int e = 0; e < 8; ++e) {
            const float4* p = (const float4*)(Wq + (size_t)(D0 + e) * (DH * NH) + n * NH);
            float s = 0.f;
#pragma unroll
            for (int i = 0; i < 8; ++i) { float4 q = p[i]; s += (q.x + q.y) + (q.z + q.w); }
            v[e] = s;
        }
    } else if (n < 2 * DH) {
#pragma unroll
        for (int e = 0; e < 8; ++e) v[e] = Wk[(size_t)(D0 + e) * DH + (n - DH)];
    } else {
#pragma unroll
        for (int e = 0; e < 8; ++e) v[e] = Wv[(size_t)(D0 + e) * DH + (n - 2 * DH)];
    }

    union { short8 s; unsigned int u[4]; } pk;
#pragma unroll
    for (int j = 0; j < 4; ++j)
        pk.u[j] = (unsigned int)f2bf(v[2 * j]) | ((unsigned int)f2bf(v[2 * j + 1]) << 16);

    const int p    = n >> 6, r = n & 63;
    const int jfr  = r >> 4, lmod = r & 15;
    const int kt   = ck >> 3;
    const int kh   = (ck >> 2) & 1;
    const int lgrp = ck & 3;
    const int lane = lgrp * 16 + lmod;
    char* dst = (char*)W3F + (size_t)p * 524288 + (size_t)kt * 8192
              + (kh * 4 + jfr) * 1024 + lane * 16;
    *(short8*)dst = pk.s;

    if (ck == 0) {
        float b;
        if (n < DH) {
            float s = 0.f;
#pragma unroll
            for (int h = 0; h < NH; ++h) s += bq[n * NH + h];
            b = s;
        } else if (n < 2 * DH) {
            b = bk[n - DH];
        } else {
            b = bv[n - 2 * DH];
        }
        bias[n] = b;
    }
}

// ---------------------------------------------------------------------------
// Kernel 2 (FUSED, BM=64, 8 waves = R19 gemm loop verbatim; EPILOGUE BARRIERS
// FIXED): epilogue barriers are now lgkm-only (s_waitcnt lgkmcnt(0); s_barrier
// ::: "memory") — __syncthreads() was draining vmcnt(0), serializing ~4 MB of
// pass-0 nt out-stores before pass 1 could start. Stores are fire-and-forget
// (no cross-wave reader; LDS hand-off only needs lgkm). R20's null additions
// (4-deep prefetch, setprio, 1-barrier loop) reverted to the measured-best
// R19 schedule (register-dbuf B 1 ahead, ping-pong av 2 ahead).
// ---------------------------------------------------------------------------
__global__ __launch_bounds__(512) void fused_mqa(const float* __restrict__ X,
                         const unsigned short* __restrict__ W3F,
                         const float* __restrict__ bias,
                         float* __restrict__ out) {
    __shared__ __align__(16) unsigned short Asm[BM * BK];   //  8 KB
    __shared__ float qsm[32 * NCOL];                        // 48 KB

    // XCD-bijective remap over 256 blocks (32 per XCD)
    const int bid  = blockIdx.x;
    const int wkid = (bid & 7) * 32 + (bid >> 3);
    const int m0   = wkid * BM;
    const int nt   = EMB / BK;                // 64

    const int t = threadIdx.x, lane = t & 63, w = t >> 6;   // w in {0..7}
    const int lmod = lane & 15, lgrp = lane >> 4;

    f32x4 acc[4][3] = {};

    // A staging (all 8 waves): wave w covers rows [w*8, w*8+8);
    // lane covers row w*8+(lane>>3); av[0] = k[(lane&7)*4..+4],
    // av[1] = k[32+(lane&7)*4..+4]  (each instr: 8 rows x 128B contiguous).
    const int arow = w * 8 + (lane >> 3);
    const float* xp = X + (size_t)(m0 + arow) * EMB + (lane & 7) * 4;
    const int ac0 = (lane & 7) >> 1;          // chunk of av[0] (av[1]: +4)
    const int ah4 = ((lane & 7) & 1) * 4;     // short offset within chunk

    // B source: wave w consumes frag cols f = w*3+j (48 cols), fragment-linear
    const char* bp[3];
#pragma unroll
    for (int j = 0; j < 3; ++j) {
        const int f = w * 3 + j;
        bp[j] = (const char*)W3F + (size_t)(f >> 2) * 524288 + (f & 3) * 1024 + lane * 16;
    }

    f32x4 avA[2], avB[2];
    short8 bfA[6], bfB[6];

#define LOAD_AV(T, AV) do { \
    const int tc_ = (T) < nt ? (T) : nt - 1; \
    AV[0] = __builtin_nontemporal_load((const f32x4*)(xp + tc_ * BK)); \
    AV[1] = __builtin_nontemporal_load((const f32x4*)(xp + tc_ * BK + 32)); \
} while (0)

#define LOAD_BF(T, BF) do { \
    const int tc_ = (T) < nt ? (T) : nt - 1; \
    _Pragma("unroll") \
    for (int j = 0; j < 3; ++j) { \
        BF[j]     = *(const short8*)(bp[j] + (size_t)tc_ * 8192); \
        BF[3 + j] = *(const short8*)(bp[j] + (size_t)tc_ * 8192 + 4096); \
    } \
} while (0)

#define WRITE_A(AV) do { \
    union { short4_t s; unsigned int u[2]; } p0, p1; \
    p0.u[0] = cvt2(AV[0].x, AV[0].y);  p0.u[1] = cvt2(AV[0].z, AV[0].w); \
    p1.u[0] = cvt2(AV[1].x, AV[1].y);  p1.u[1] = cvt2(AV[1].z, AV[1].w); \
    *(short4_t*)(&Asm[arow * BK + ((ac0 ^ (arow & 7)) << 3) + ah4]) = p0.s; \
    *(short4_t*)(&Asm[arow * BK + (((ac0 + 4) ^ (arow & 7)) << 3) + ah4]) = p1.s; \
} while (0)

#define COMPUTE(BF) do { \
    _Pragma("unroll") \
    for (int kh = 0; kh < 2; ++kh) { \
        const int cs = ((kh * 4 + lgrp) ^ (lmod & 7)) * 8; \
        short8 af[4]; \
        _Pragma("unroll") \
        for (int i = 0; i < 4; ++i) \
            af[i] = *(const short8*)(&Asm[(i * 16 + lmod) * BK + cs]); \
        _Pragma("unroll") \
        for (int i = 0; i < 4; ++i) \
            _Pragma("unroll") \
            for (int j = 0; j < 3; ++j) \
                acc[i][j] = __builtin_amdgcn_mfma_f32_16x16x32_bf16(af[i], BF[kh * 3 + j], acc[i][j], 0, 0, 0); \
    } \
} while (0)

// barriers: compile-time order pinned ("memory"), counters NOT drained.
// WBAR/EBAR drain lgkm only (LDS visibility); vmcnt stays outstanding.
#define ABAR()  do { asm volatile("s_barrier" ::: "memory"); } while (0)
#define EBAR()  do { asm volatile("s_waitcnt lgkmcnt(0)\n\ts_barrier" ::: "memory"); } while (0)

    // prologue: issue av(0), av(1), bf(0)
    LOAD_AV(0, avA);
    LOAD_AV(1, avB);
    LOAD_BF(0, bfA);

    for (int tt = 0; tt < nt; tt += 2) {
        // even sub-iter: tile tt (avA, bfA)
        ABAR();                               // A-readers of tile tt-1 done
        WRITE_A(avA);                         // counted vmcnt wait on avA only
        EBAR();                               // ds_writes visible to all waves
        LOAD_BF(tt + 1, bfB);                 // in flight across next barriers
        LOAD_AV(tt + 2, avA);                 // 2 tiles of slack
        COMPUTE(bfA);
        // odd sub-iter: tile tt+1 (avB, bfB)
        ABAR();
        WRITE_A(avB);
        EBAR();
        LOAD_BF(tt + 2, bfA);
        LOAD_AV(tt + 3, avB);
        COMPUTE(bfB);
    }

    // ---- epilogue: two passes of 32 tokens each through the 48-KB qsm.
    // lgkm-only barriers: pass-0 nt stores stay in flight under pass 1.
    const float c = 0.088388347648318447f * 1.4426950408889634f; // scale*log2(e)
#pragma unroll
    for (int pass = 0; pass < 2; ++pass) {
        EBAR();                               // prev qsm readers done (LDS only)
#pragma unroll
        for (int j = 0; j < 3; ++j) {
            const int col = w * 48 + j * 16 + lmod;
            const float bj = bias[col];
#pragma unroll
            for (int i2 = 0; i2 < 2; ++i2) {
                const int row = i2 * 16 + (lgrp << 2);   // row within pass
#pragma unroll
                for (int r = 0; r < 4; ++r)
                    qsm[(row + r) * NCOL + col] = acc[pass * 2 + i2][j][r] + bj;
            }
        }
        EBAR();                               // qsm pass resident (LDS only)

        for (int tok = w; tok < 32; tok += 8) {
            const float* row = &qsm[tok * NCOL];
            const float q0  = row[lane],       q1  = row[64 + lane];
            const float kk0 = row[128 + lane], kk1 = row[192 + lane];

            float lmax = fmaxf(kk0, kk1), lmin = fminf(kk0, kk1);
#pragma unroll
            for (int off = 32; off; off >>= 1) {
                lmax = fmaxf(lmax, __shfl_xor(lmax, off));
                lmin = fminf(lmin, __shfl_xor(lmin, off));
            }

            const float a0 = q0 * c, a1 = q1 * c;
            const float m0v = (a0 >= 0.f) ? a0 * lmax : a0 * lmin;
            const float m1v = (a1 >= 0.f) ? a1 * lmax : a1 * lmin;

            float s00 = 0.f, s01 = 0.f, s10 = 0.f, s11 = 0.f;
#pragma unroll 8
            for (int e = 0; e < DH; ++e) {
                const float kv = row[128 + e];    // broadcast LDS read
                const float vv = row[256 + e];
                const float p0 = exp2_hw(fmaf(a0, kv, -m0v));
                const float p1 = exp2_hw(fmaf(a1, kv, -m1v));
                s00 += p0;  s01 = fmaf(p0, vv, s01);
                s10 += p1;  s11 = fmaf(p1, vv, s11);
            }
            const float o0 = s01 / s00;           // o[d], d = lane
            const float o1 = s11 / s10;           // o[d], d = 64 + lane

            float* orow = out + (size_t)(m0 + pass * 32 + tok) * (DH * NH);
#pragma unroll
            for (int it = 0; it < 16; ++it) {
                const int idx = it * 64 + lane;              // float4 index
                const int src = (it & 7) * 8 + (lane >> 3);  // d & 63
                const float val = (it < 8) ? __shfl(o0, src) : __shfl(o1, src);
                f32x4 f4 = {val, val, val, val};
                __builtin_nontemporal_store(f4, (f32x4*)(orow + idx * 4));
            }
        }
    }
#undef LOAD_AV
#undef LOAD_BF
#undef WRITE_A
#undef COMPUTE
#undef ABAR
#undef EBAR
}

// ---------------------------------------------------------------------------
extern "C" void kernel_launch(void* const* d_in, const int* in_sizes, int n_in,
                              void* d_out, int out_size, void* d_ws, size_t ws_size,
                              hipStream_t stream) {
    const float* x  = (const float*)d_in[0];
    const float* Wq = (const float*)d_in[1];
    const float* bq = (const float*)d_in[2];
    const float* Wk = (const float*)d_in[3];
    const float* bk = (const float*)d_in[4];
    const float* Wv = (const float*)d_in[5];
    const float* bv = (const float*)d_in[6];
    float* out = (float*)d_out;

    char* ws = (char*)d_ws;
    unsigned short* W3F = (unsigned short*)ws;       // 6*524288 = 3,145,728 B
    float* bias = (float*)(ws + 3145728);            // 1,536 B

    prep_w<<<(NCOL * 512) / 256, 256, 0, stream>>>(Wq, bq, Wk, bk, Wv, bv, W3F, bias);
    fused_mqa<<<NTOK / BM, 512, 0, stream>>>(x, W3F, bias, out);
}